// Round 1
// baseline (78.332 us; speedup 1.0000x reference)
//
#include <hip/hip_runtime.h>
#include <hip/hip_bf16.h>
#include <stdint.h>

// out[b,j] = sum_{i,k} softmax(alphas[i,j,:])[k] * coeffs[i,j,k] * prim_k(x[b,i])
//         == P @ W2,  P[b, kg] = prim_op(x[b,i]),  W2[kg][j]
// k-ordering remapped so the MFMA A-fragment is one cacheline/lane:
//   kg = c*32 + quad*8 + j  <->  i = quad*16 + c , op = j   (c=0..15, quad=0..3)
//
// R6: M-blocked MFMA loop — each wave owns TWO 16-row tiles (32 rows x 64 cols).
//  - 256 blocks x 512 threads (8 waves); block covers 256 rows. 1 block/CU,
//    8 waves/CU, LDS 64 KB.
//  - Per K-step: 4 ds_read_b128 B-fragments are read ONCE and feed 8 MFMAs
//    (2 A-frags) -> LDS read traffic halved vs R5 (1 MB -> 512 KB per block).
//  - Phase B re-indexed: LDS write is LINEAR in tid (conflict-free; R5's
//    scattered write was an 8-way bank conflict); the scatter moved to the
//    global-read side (512 B segments, still coalesced, L2/L3-hot).
//  - __launch_bounds__(512,2): VGPR cap 256 (was 128) so the compiler can
//    pipeline b-fragment reads across the unrolled K loop. Occupancy is
//    grid/LDS-limited to 8 waves/CU either way.
//  - HW transcendentals: v_exp_f32 / v_log_f32 / v_sin_f32 / v_rcp_f32.
//    x in (0.5,1.5): no range reduction needed; err << bf16 rounding.
//  - B reads: wlds + c*2048 + lane*8 -> contiguous 1KB/wave ds_read_b128,
//    conflict-free.  C/D: col=lane&15, row=quad*4+reg (verified layout).

typedef __bf16 bf16x8 __attribute__((ext_vector_type(8)));
typedef float f32x4 __attribute__((ext_vector_type(4)));

#define LOG2E   1.4426950408889634f
#define LN2     0.6931471805599453f
#define INV2PI  0.15915494309189535f

__device__ __forceinline__ bf16x8 prim_frag(float xv) {
    const float x2 = xv * xv;
    bf16x8 a;
    a[0] = (__bf16)0.0f;                                        // none
    a[1] = (__bf16)xv;                                          // linear
    a[2] = (__bf16)x2;                                          // x^2
    a[3] = (__bf16)(x2 * xv);                                   // x^3
    a[4] = (__bf16)__builtin_amdgcn_exp2f(xv * LOG2E);          // exp
    a[5] = (__bf16)(__builtin_amdgcn_logf(xv) * LN2);           // ln
    a[6] = (__bf16)__builtin_amdgcn_rcpf(xv);                   // 1/x
    a[7] = (__bf16)__builtin_amdgcn_sinf(xv * INV2PI);          // sin
    return a;
}

__global__ __launch_bounds__(512, 2) void darts_fused(const float* __restrict__ x,
                                                      const float* __restrict__ alphas,
                                                      const float* __restrict__ coeffs,
                                                      float* __restrict__ out) {
    __shared__ __bf16 wlds[32768];   // 64 KB, B-fragment order

    const int tid  = threadIdx.x;
    const int lane = tid & 63;
    const int wv   = tid >> 6;       // 0..7
    const int m    = lane & 15;      // A row within 16-tile
    const int q    = lane >> 4;      // quad

    // ---- phase A: issue x loads first (HBM latency hides behind phase B) ----
    // Wave wv owns rows wv*32 .. wv*32+31 (two 16-row tiles).
    const int row0 = blockIdx.x * 256 + wv * 32 + m;
    const float* xp0 = x + row0 * 64 + q * 16;
    f32x4 x00 = *(const f32x4*)(xp0 + 0);
    f32x4 x01 = *(const f32x4*)(xp0 + 4);
    f32x4 x02 = *(const f32x4*)(xp0 + 8);
    f32x4 x03 = *(const f32x4*)(xp0 + 12);
    const float* xp1 = xp0 + 16 * 64;                 // tile 1 = rows +16
    f32x4 x10 = *(const f32x4*)(xp1 + 0);
    f32x4 x11 = *(const f32x4*)(xp1 + 4);
    f32x4 x12 = *(const f32x4*)(xp1 + 8);
    f32x4 x13 = *(const f32x4*)(xp1 + 12);

    // ---- phase B: W2 = softmax(alphas)*coeffs -> LDS (bf16, frag order) -----
    // Iterate LINEARLY over fragment positions gp; LDS write is tid-contiguous
    // (16 B/lane, conflict-free). Source index is the scattered side:
    //   gp = cc*256 + t*64 + qq*16 + nl ; unit (i = qq*16+cc, n = t*16+nl)
    //   src element = (i*64 + n)*8. 4096 units / 512 threads = 8 each.
#pragma unroll
    for (int u = 0; u < 8; ++u) {
        const int gp = u * 512 + tid;
        const int cc = gp >> 8;
        const int t  = (gp >> 6) & 3;
        const int qq = (gp >> 4) & 3;
        const int nl = gp & 15;
        const int src = ((qq * 16 + cc) * 64 + t * 16 + nl) * 8;
        const float* a  = alphas + src;
        const float* cf = coeffs + src;

        float e[8], s = 0.f;
#pragma unroll
        for (int k = 0; k < 8; ++k) {
            e[k] = __builtin_amdgcn_exp2f(a[k] * LOG2E);   // |a|<0.03: no max-sub
            s += e[k];
        }
        const float inv = __builtin_amdgcn_rcpf(s);

        bf16x8 w;
#pragma unroll
        for (int k = 0; k < 8; ++k) w[k] = (__bf16)(e[k] * inv * cf[k]);

        *(bf16x8*)(wlds + gp * 8) = w;                     // linear: no conflicts
    }
    __syncthreads();

    // ---- phase C: MFMA main loop, Mt=2 row tiles per wave -------------------
    float xa0[16], xa1[16];
#pragma unroll
    for (int c = 0; c < 4; ++c) {
        xa0[c] = x00[c]; xa0[4 + c] = x01[c]; xa0[8 + c] = x02[c]; xa0[12 + c] = x03[c];
        xa1[c] = x10[c]; xa1[4 + c] = x11[c]; xa1[8 + c] = x12[c]; xa1[12 + c] = x13[c];
    }

    f32x4 acc00 = {0.f, 0.f, 0.f, 0.f}, acc01 = {0.f, 0.f, 0.f, 0.f};
    f32x4 acc02 = {0.f, 0.f, 0.f, 0.f}, acc03 = {0.f, 0.f, 0.f, 0.f};
    f32x4 acc10 = {0.f, 0.f, 0.f, 0.f}, acc11 = {0.f, 0.f, 0.f, 0.f};
    f32x4 acc12 = {0.f, 0.f, 0.f, 0.f}, acc13 = {0.f, 0.f, 0.f, 0.f};

#pragma unroll
    for (int c = 0; c < 16; ++c) {
        bf16x8 a0 = prim_frag(xa0[c]);
        bf16x8 a1 = prim_frag(xa1[c]);
        const __bf16* bb = wlds + c * 2048 + lane * 8;
        bf16x8 b0 = *(const bf16x8*)(bb);
        bf16x8 b1 = *(const bf16x8*)(bb + 512);
        bf16x8 b2 = *(const bf16x8*)(bb + 1024);
        bf16x8 b3 = *(const bf16x8*)(bb + 1536);
        acc00 = __builtin_amdgcn_mfma_f32_16x16x32_bf16(a0, b0, acc00, 0, 0, 0);
        acc10 = __builtin_amdgcn_mfma_f32_16x16x32_bf16(a1, b0, acc10, 0, 0, 0);
        acc01 = __builtin_amdgcn_mfma_f32_16x16x32_bf16(a0, b1, acc01, 0, 0, 0);
        acc11 = __builtin_amdgcn_mfma_f32_16x16x32_bf16(a1, b1, acc11, 0, 0, 0);
        acc02 = __builtin_amdgcn_mfma_f32_16x16x32_bf16(a0, b2, acc02, 0, 0, 0);
        acc12 = __builtin_amdgcn_mfma_f32_16x16x32_bf16(a1, b2, acc12, 0, 0, 0);
        acc03 = __builtin_amdgcn_mfma_f32_16x16x32_bf16(a0, b3, acc03, 0, 0, 0);
        acc13 = __builtin_amdgcn_mfma_f32_16x16x32_bf16(a1, b3, acc13, 0, 0, 0);
    }

    // ---- epilogue: C layout col=lane&15, row=q*4+r (per tile) ---------------
    float* o0 = out + (blockIdx.x * 256 + wv * 32 + q * 4) * 64 + m;
    float* o1 = o0 + 16 * 64;
#pragma unroll
    for (int r = 0; r < 4; ++r) {
        o0[r * 64 + 0]  = acc00[r];
        o0[r * 64 + 16] = acc01[r];
        o0[r * 64 + 32] = acc02[r];
        o0[r * 64 + 48] = acc03[r];
        o1[r * 64 + 0]  = acc10[r];
        o1[r * 64 + 16] = acc11[r];
        o1[r * 64 + 32] = acc12[r];
        o1[r * 64 + 48] = acc13[r];
    }
}

extern "C" void kernel_launch(void* const* d_in, const int* in_sizes, int n_in,
                              void* d_out, int out_size, void* d_ws, size_t ws_size,
                              hipStream_t stream) {
    const float* x      = (const float*)d_in[0];
    const float* alphas = (const float*)d_in[1];
    const float* coeffs = (const float*)d_in[2];
    float* out = (float*)d_out;
    (void)d_ws; (void)ws_size;

    darts_fused<<<256, 512, 0, stream>>>(x, alphas, coeffs, out);
}